// Round 12
// baseline (218.715 us; speedup 1.0000x reference)
//
#include <hip/hip_runtime.h>
#include <hip/hip_bf16.h>

#define NTOT 1048576
#define NSEG 4096
#define HDIM 128
#define ODIM 256
#define BN   64
#define GRID1 1024
#define TPB  (NTOT / (BN * GRID1))   // 16 tiles per block

typedef __attribute__((ext_vector_type(8))) short bf16x8;
typedef __attribute__((ext_vector_type(4))) float f32x4;
typedef __attribute__((ext_vector_type(4))) unsigned int u32x4;

typedef const __attribute__((address_space(1))) unsigned int* gp_t;
typedef __attribute__((address_space(3))) unsigned int* lp_t;

// HW packed f32->bf16 RNE (no builtin on gfx950)
__device__ __forceinline__ unsigned int cvt_pk(float lo, float hi) {
    unsigned int r;
    asm("v_cvt_pk_bf16_f32 %0, %1, %2" : "=v"(r) : "v"(lo), "v"(hi));
    return r;
}

// zero sumx (1M floats) + convert W1 (32768 f32 -> 16384 packed u32), one dispatch
__global__ void zero_convert(const float* __restrict__ W1, unsigned int* __restrict__ W1b,
                             float* __restrict__ sumx) {
    int gid = blockIdx.x * 256 + threadIdx.x;
    sumx[gid] = 0.0f;
    if (gid < (ODIM * HDIM / 2)) {
        float2 v = *(const float2*)(W1 + 2 * gid);
        W1b[gid] = cvt_pk(v.x, v.y);
    }
}

// R11 + 4 sub-phases per tile (T3/T4): DMA chunk j of wave wv = full-K rows
// 8j+2wv..+2, so row-group mf only needs chunks {2mf,2mf+1} per wave. Sub-phase
// waits vmcnt(14-2mf) -> compute starts after 2 chunks land, remaining DMA
// service overlaps MFMA/tanh. End-of-iter vmcnt(8) retires reduce-atomics so
// counted waits stay exact (atomics would otherwise inflate vmcnt).
__global__ __launch_bounds__(256, 2)
void stage1(const float* __restrict__ x, const int* __restrict__ batch,
            const unsigned short* __restrict__ W1b, const float* __restrict__ b1,
            float* __restrict__ sumx) {
    __shared__ __align__(16) float xbuf[2][BN * HDIM];   // 2 x 32 KB swizzled f32 tiles
    __shared__ int segAll[TPB * BN];                     // 4 KB

    const int t    = threadIdx.x;
    const int lane = t & 63;
    const int wv   = t >> 6;
    const int l15  = lane & 15;
    const int lhi  = (lane >> 4) & 3;

    // dtype probe: int64 little-endian => odd (high) words are 0
    const bool is64 = (batch[NTOT - 1] == 0);
    const long r0 = (long)blockIdx.x * (TPB * BN);
    const char* xb = (const char*)(x + r0 * HDIM);

    // source byte-offsets within a 32KB tile: row-contiguous, granule-XOR-swizzled
    int soff[8];
    #pragma unroll
    for (int j = 0; j < 8; ++j) {
        int c = j * 256 + wv * 64 + lane;
        int row = c >> 5, g = c & 31;
        soff[j] = row * 512 + ((g << 4) ^ ((row & 7) << 4));
    }

    // prologue: stage tile 0
    #pragma unroll
    for (int j = 0; j < 8; ++j)
        __builtin_amdgcn_global_load_lds((gp_t)(xb + soff[j]),
                                         (lp_t)((char*)&xbuf[0][0] + (j * 256 + wv * 64) * 16), 16, 0, 0);
    __builtin_amdgcn_sched_barrier(0);

    // while DMA flies: seg table, W1 B-fragments (64 VGPR), bias
    for (int i = t; i < TPB * BN; i += 256) {
        long idx = r0 + i;
        segAll[i] = batch[is64 ? 2 * idx : idx];
    }
    bf16x8 bfr[4][4];   // [nf][ks]; wave wv owns cols [wv*64, wv*64+64)
    #pragma unroll
    for (int nf = 0; nf < 4; ++nf)
        #pragma unroll
        for (int ks = 0; ks < 4; ++ks)
            bfr[nf][ks] = *(const bf16x8*)(W1b + (wv * 64 + nf * 16 + l15) * HDIM + ks * 32 + lhi * 8);
    float bias[4];
    #pragma unroll
    for (int nf = 0; nf < 4; ++nf) bias[nf] = b1[wv * 64 + nf * 16 + l15];

    asm volatile("s_waitcnt vmcnt(0) lgkmcnt(0)" ::: "memory");
    __builtin_amdgcn_sched_barrier(0);
    __builtin_amdgcn_s_barrier();

    for (int g = 0; g < TPB; ++g) {
        const int nb = g & 1;
        const bool more = (g + 1 < TPB);

        if (more) {
            // issue prefetch DMAs for tile g+1 (j-order defines the vmcnt ladder)
            const char* src = xb + (size_t)(g + 1) * (BN * HDIM * 4);
            char* dst = (char*)&xbuf[nb ^ 1][0];
            #pragma unroll
            for (int j = 0; j < 8; ++j)
                __builtin_amdgcn_global_load_lds((gp_t)(src + soff[j]),
                                                 (lp_t)(dst + (j * 256 + wv * 64) * 16), 16, 0, 0);
            __builtin_amdgcn_sched_barrier(0);
        }

        const char* tile = (const char*)&xbuf[nb][0];
        f32x4 acc[4][4];

        #pragma unroll
        for (int mf = 0; mf < 4; ++mf) {
            // wait: my chunks j<=2mf+1 of tile g landed (+8 prefetch outstanding if more)
            if (more) {
                if      (mf == 0) asm volatile("s_waitcnt vmcnt(14)" ::: "memory");
                else if (mf == 1) asm volatile("s_waitcnt vmcnt(12)" ::: "memory");
                else if (mf == 2) asm volatile("s_waitcnt vmcnt(10)" ::: "memory");
                else              asm volatile("s_waitcnt vmcnt(8)"  ::: "memory");
            } else {
                if      (mf == 0) asm volatile("s_waitcnt vmcnt(6)" ::: "memory");
                else if (mf == 1) asm volatile("s_waitcnt vmcnt(4)" ::: "memory");
                else if (mf == 2) asm volatile("s_waitcnt vmcnt(2)" ::: "memory");
                else              asm volatile("s_waitcnt vmcnt(0)" ::: "memory");
            }
            __builtin_amdgcn_sched_barrier(0);
            __builtin_amdgcn_s_barrier();        // all waves' chunks {2mf,2mf+1} landed
            __builtin_amdgcn_sched_barrier(0);

            // ---- compute row-group mf: ds_read + cvt + 16 MFMA + tanh ----
            #pragma unroll
            for (int nf = 0; nf < 4; ++nf) {
                const float bb = bias[nf];
                acc[mf][nf] = (f32x4){bb, bb, bb, bb};
            }
            const int m  = mf * 16 + l15;
            const int rb = m * 512;
            const int sw = (m & 7) << 4;
            #pragma unroll
            for (int ks = 0; ks < 4; ++ks) {
                const int kb = ks * 128 + lhi * 32;
                f32x4 u = *(const f32x4*)(tile + rb + (kb ^ sw));
                f32x4 v = *(const f32x4*)(tile + rb + ((kb + 16) ^ sw));
                u32x4 w;
                w.x = cvt_pk(u.x, u.y); w.y = cvt_pk(u.z, u.w);
                w.z = cvt_pk(v.x, v.y); w.w = cvt_pk(v.z, v.w);
                bf16x8 af = __builtin_bit_cast(bf16x8, w);
                #pragma unroll
                for (int nf = 0; nf < 4; ++nf)
                    acc[mf][nf] = __builtin_amdgcn_mfma_f32_16x16x32_bf16(af, bfr[nf][ks], acc[mf][nf], 0, 0, 0);
            }
            // tanh(s) = 1 - 2/(1 + 2^(s*2*log2e))
            #pragma unroll
            for (int nf = 0; nf < 4; ++nf)
                #pragma unroll
                for (int r = 0; r < 4; ++r) {
                    float e = exp2f(acc[mf][nf][r] * 2.885390081777927f);
                    acc[mf][nf][r] = 1.0f - 2.0f * __builtin_amdgcn_rcpf(1.0f + e);
                }
        }

        // in-register segmented reduction (batch sorted); atomics flushed below
        const int* segc = &segAll[g * BN];
        unsigned long long bmask;
        {
            int s_here = segc[lane];
            int s_prev = (lane > 0) ? segc[lane - 1] : s_here;
            bmask = __ballot(s_here != s_prev);
        }
        int start = 0;
        unsigned long long rem = bmask;
        for (;;) {
            const int end = rem ? (int)__builtin_ctzll(rem) : BN;
            const int sid = segc[start];
            float p0 = 0.f, p1 = 0.f, p2 = 0.f, p3 = 0.f;
            #pragma unroll
            for (int mf = 0; mf < 4; ++mf)
                #pragma unroll
                for (int r = 0; r < 4; ++r) {
                    int row = mf * 16 + lhi * 4 + r;
                    float w = ((unsigned)(row - start) < (unsigned)(end - start)) ? 1.0f : 0.0f;
                    p0 = fmaf(w, acc[mf][0][r], p0);
                    p1 = fmaf(w, acc[mf][1][r], p1);
                    p2 = fmaf(w, acc[mf][2][r], p2);
                    p3 = fmaf(w, acc[mf][3][r], p3);
                }
            p0 += __shfl_xor(p0, 16); p0 += __shfl_xor(p0, 32);
            p1 += __shfl_xor(p1, 16); p1 += __shfl_xor(p1, 32);
            p2 += __shfl_xor(p2, 16); p2 += __shfl_xor(p2, 32);
            p3 += __shfl_xor(p3, 16); p3 += __shfl_xor(p3, 32);
            if (lhi == 0) {
                float* base = sumx + (long)sid * ODIM + wv * 64 + l15;
                atomicAdd(base +  0, p0);
                atomicAdd(base + 16, p1);
                atomicAdd(base + 32, p2);
                atomicAdd(base + 48, p3);
            }
            if (rem == 0) break;
            start = end;
            rem &= rem - 1;
        }

        // retire atomics (keep the 8 prefetch DMAs flying) + free buffer for next DMA
        if (more) asm volatile("s_waitcnt vmcnt(8) lgkmcnt(0)" ::: "memory");
        else      asm volatile("s_waitcnt vmcnt(0) lgkmcnt(0)" ::: "memory");
        __builtin_amdgcn_sched_barrier(0);
        __builtin_amdgcn_s_barrier();
        __builtin_amdgcn_sched_barrier(0);
    }
}

// y[g][h] = b2[h] + sum_o sumx[g][o] * W2[h][o]   (fp32, 268 MFLOP)
__global__ __launch_bounds__(256)
void stage2(const float* __restrict__ sumx, const float* __restrict__ W2,
            const float* __restrict__ b2, float* __restrict__ y) {
    __shared__ float sx[16 * 256];
    const int t = threadIdx.x;
    const long g0 = (long)blockIdx.x * 16;
    #pragma unroll
    for (int i = 0; i < 16; ++i)
        sx[i * 256 + t] = sumx[(g0 + i) * 256 + t];
    __syncthreads();
    const int h = t & 127;
    const int gl0 = (t >> 7) * 8;
    float acc[8] = {0, 0, 0, 0, 0, 0, 0, 0};
    const float* w = W2 + h * 256;
    for (int o4 = 0; o4 < 64; ++o4) {
        float4 wvv = *(const float4*)(w + o4 * 4);
        #pragma unroll
        for (int gl = 0; gl < 8; ++gl) {
            const float* sr = &sx[(gl0 + gl) * 256 + o4 * 4];
            acc[gl] += sr[0] * wvv.x + sr[1] * wvv.y + sr[2] * wvv.z + sr[3] * wvv.w;
        }
    }
    float bb = b2[h];
    #pragma unroll
    for (int gl = 0; gl < 8; ++gl)
        y[(g0 + gl0 + gl) * 128 + h] = acc[gl] + bb;
}

extern "C" void kernel_launch(void* const* d_in, const int* in_sizes, int n_in,
                              void* d_out, int out_size, void* d_ws, size_t ws_size,
                              hipStream_t stream) {
    const float* x   = (const float*)d_in[0];
    const int* batch = (const int*)d_in[1];
    const float* W1  = (const float*)d_in[2];
    const float* b1  = (const float*)d_in[3];
    const float* W2  = (const float*)d_in[4];
    const float* b2  = (const float*)d_in[5];
    float* y = (float*)d_out;

    float* sumx = (float*)d_ws;                                                     // 4 MB
    unsigned short* W1b = (unsigned short*)((char*)d_ws + (size_t)NSEG * ODIM * 4); // 64 KB

    zero_convert<<<dim3(NSEG), dim3(256), 0, stream>>>(W1, (unsigned int*)W1b, sumx);
    stage1<<<dim3(GRID1), dim3(256), 0, stream>>>(x, batch, W1b, b1, sumx);
    stage2<<<dim3(NSEG / 16), dim3(256), 0, stream>>>(sumx, W2, b2, y);
}